// Round 1
// baseline (1127.524 us; speedup 1.0000x reference)
//
#include <hip/hip_runtime.h>
#include <math.h>

#define BSZ 128
#define RNN 1024
#define NF  200
#define VOCAB 50257
#define NL  (VOCAB + NF)   // 50457

// ---------------- K1: attnin1/2 = tanh(h*g + b) ----------------
__global__ void k_attnin(const float* __restrict__ hid,
                         const float* __restrict__ g1, const float* __restrict__ b1,
                         const float* __restrict__ g2, const float* __restrict__ b2,
                         float* __restrict__ a1, float* __restrict__ a2) {
    int i = blockIdx.x * blockDim.x + threadIdx.x;   // 0..131071
    int k = i & (RNN - 1);
    float h = hid[i];
    a1[i] = tanhf(h * g1[k] + b1[k]);
    a2[i] = tanhf(h * g2[k] + b2[k]);
}

// ---------------- K2: ascores = a1 @ s^T ; ascores2 -> logits tail ----------------
// one wave per (b,f); s-row loaded once, dotted with both queries
__global__ void k_scores(const float* __restrict__ a1, const float* __restrict__ a2,
                         const float* __restrict__ s,
                         float* __restrict__ ascores, float* __restrict__ out) {
    int wave = (int)((blockIdx.x * blockDim.x + threadIdx.x) >> 6);
    int lane = threadIdx.x & 63;
    if (wave >= BSZ * NF) return;
    int b = wave / NF, f = wave % NF;
    const float4* sv = (const float4*)(s + (size_t)f * RNN);
    const float4* v1 = (const float4*)(a1 + (size_t)b * RNN);
    const float4* v2 = (const float4*)(a2 + (size_t)b * RNN);
    float acc1 = 0.f, acc2 = 0.f;
    #pragma unroll
    for (int i = lane; i < RNN / 4; i += 64) {
        float4 sx = sv[i], x1 = v1[i], x2 = v2[i];
        acc1 += sx.x * x1.x + sx.y * x1.y + sx.z * x1.z + sx.w * x1.w;
        acc2 += sx.x * x2.x + sx.y * x2.y + sx.z * x2.z + sx.w * x2.w;
    }
    #pragma unroll
    for (int m = 32; m >= 1; m >>= 1) {
        acc1 += __shfl_xor(acc1, m, 64);
        acc2 += __shfl_xor(acc2, m, 64);
    }
    if (lane == 0) {
        ascores[b * NF + f] = acc1;
        out[(size_t)b * NL + VOCAB + f] = acc2;   // raw logit; softmaxed later
    }
}

// ---------------- K3: softmax over NF (in place) ----------------
__global__ void k_softmax_small(float* __restrict__ sc) {
    int b = blockIdx.x;
    int t = threadIdx.x;                // 256 threads
    __shared__ float red[256];
    float x = (t < NF) ? sc[b * NF + t] : -INFINITY;
    red[t] = x; __syncthreads();
    for (int s = 128; s >= 1; s >>= 1) {
        if (t < s) red[t] = fmaxf(red[t], red[t + s]);
        __syncthreads();
    }
    float mx = red[0]; __syncthreads();
    float e = (t < NF) ? expf(x - mx) : 0.f;
    red[t] = e; __syncthreads();
    for (int s = 128; s >= 1; s >>= 1) {
        if (t < s) red[t] += red[t + s];
        __syncthreads();
    }
    float inv = 1.f / red[0];
    if (t < NF) sc[b * NF + t] = e * inv;
}

// ---------------- K4: ctx = aprobs @ s ; state = tanh([h,ctx]*og+ob) ----------------
__global__ void k_ctx_state(const float* __restrict__ hid, const float* __restrict__ aprobs,
                            const float* __restrict__ s, const float* __restrict__ og,
                            const float* __restrict__ ob, float* __restrict__ state) {
    int b = blockIdx.y;
    int j = blockIdx.x * 256 + threadIdx.x;   // 0..2047
    __shared__ float ap[NF];
    if (threadIdx.x < NF) ap[threadIdx.x] = aprobs[b * NF + threadIdx.x];
    __syncthreads();
    float v;
    if (j < RNN) {
        v = hid[(size_t)b * RNN + j];
    } else {
        int jj = j - RNN;
        float acc = 0.f;
        #pragma unroll 8
        for (int f = 0; f < NF; ++f) acc += ap[f] * s[(size_t)f * RNN + jj];
        v = acc;
    }
    state[(size_t)b * 2048 + j] = tanhf(v * og[j] + ob[j]);
}

// ---------------- K5: logits = state @ W^T + bias ----------------
// 128x128 tile, BK=32, 8x8 micro-tile per thread, LDS-staged
#define BN 128
#define BK 32
__global__ __launch_bounds__(256) void k_gemm(const float* __restrict__ A,    // 128 x 2048
                                              const float* __restrict__ W,    // VOCAB x 2048
                                              const float* __restrict__ bias, // VOCAB
                                              float* __restrict__ out) {
    __shared__ float As[BK][BSZ];   // 16 KB
    __shared__ float Bs[BK][BN];    // 16 KB
    int n0 = blockIdx.x * BN;
    int tid = threadIdx.x;
    int tx = tid & 15, ty = tid >> 4;   // 16 x 16 thread grid
    float acc[8][8] = {};
    for (int k0 = 0; k0 < 2048; k0 += BK) {
        #pragma unroll
        for (int i = 0; i < 4; ++i) {       // stage A: 1024 float4s / 256 threads
            int idx = tid + i * 256;
            int row = idx >> 3, c4 = idx & 7;
            float4 v = *(const float4*)(A + (size_t)row * 2048 + k0 + c4 * 4);
            int kk = c4 * 4;
            As[kk + 0][row] = v.x; As[kk + 1][row] = v.y;
            As[kk + 2][row] = v.z; As[kk + 3][row] = v.w;
        }
        #pragma unroll
        for (int i = 0; i < 4; ++i) {       // stage B
            int idx = tid + i * 256;
            int row = idx >> 3, c4 = idx & 7;
            int n = n0 + row;
            float4 v = make_float4(0.f, 0.f, 0.f, 0.f);
            if (n < VOCAB) v = *(const float4*)(W + (size_t)n * 2048 + k0 + c4 * 4);
            int kk = c4 * 4;
            Bs[kk + 0][row] = v.x; Bs[kk + 1][row] = v.y;
            Bs[kk + 2][row] = v.z; Bs[kk + 3][row] = v.w;
        }
        __syncthreads();
        #pragma unroll
        for (int k = 0; k < BK; ++k) {
            float a[8], bb[8];
            *(float4*)&a[0]  = *(const float4*)&As[k][ty * 8];
            *(float4*)&a[4]  = *(const float4*)&As[k][ty * 8 + 4];
            *(float4*)&bb[0] = *(const float4*)&Bs[k][tx * 8];
            *(float4*)&bb[4] = *(const float4*)&Bs[k][tx * 8 + 4];
            #pragma unroll
            for (int i = 0; i < 8; ++i)
                #pragma unroll
                for (int j = 0; j < 8; ++j)
                    acc[i][j] += a[i] * bb[j];
        }
        __syncthreads();
    }
    #pragma unroll
    for (int i = 0; i < 8; ++i) {
        int m = ty * 8 + i;
        #pragma unroll
        for (int j = 0; j < 8; ++j) {
            int n = n0 + tx * 8 + j;
            if (n < VOCAB) out[(size_t)m * NL + n] = acc[i][j] + bias[n];
        }
    }
}

// ---------------- K6: per-row online max / sum-exp over NL ----------------
__global__ void k_rowstats(const float* __restrict__ out, float* __restrict__ stats) {
    int b = blockIdx.x;
    int t = threadIdx.x;   // 256
    const float* row = out + (size_t)b * NL;
    float m = -INFINITY, ssum = 0.f;
    for (int i = t; i < NL; i += 256) {
        float x = row[i];
        float M = fmaxf(m, x);
        ssum = ssum * expf(m - M) + expf(x - M);
        m = M;
    }
    __shared__ float ms[256], ss[256];
    ms[t] = m; ss[t] = ssum; __syncthreads();
    for (int s = 128; s >= 1; s >>= 1) {
        if (t < s) {
            float m2 = ms[t + s], s2 = ss[t + s];
            float M = fmaxf(ms[t], m2);
            ss[t] = ss[t] * expf(ms[t] - M) + s2 * expf(m2 - M);
            ms[t] = M;
        }
        __syncthreads();
    }
    if (t == 0) { stats[b] = ms[0]; stats[BSZ + b] = 1.f / ss[0]; }
}

// ---------------- K7: normalize in place ----------------
__global__ void k_norm(float* __restrict__ out, const float* __restrict__ stats) {
    int b = blockIdx.y;
    int i = blockIdx.x * 256 + threadIdx.x;
    if (i < NL) {
        size_t idx = (size_t)b * NL + i;
        out[idx] = expf(out[idx] - stats[b]) * stats[BSZ + b];
    }
}

extern "C" void kernel_launch(void* const* d_in, const int* in_sizes, int n_in,
                              void* d_out, int out_size, void* d_ws, size_t ws_size,
                              hipStream_t stream) {
    const float* hid   = (const float*)d_in[0];
    const float* sfe   = (const float*)d_in[1];
    const float* ag    = (const float*)d_in[2];
    const float* ab    = (const float*)d_in[3];
    const float* og    = (const float*)d_in[4];
    const float* ob    = (const float*)d_in[5];
    const float* a2g   = (const float*)d_in[6];
    const float* a2b   = (const float*)d_in[7];
    const float* dec_w = (const float*)d_in[8];
    const float* dec_b = (const float*)d_in[9];
    float* out = (float*)d_out;

    float* ws      = (float*)d_ws;
    float* attnin1 = ws;                 // 131072
    float* attnin2 = ws + 131072;        // 131072
    float* ascores = ws + 262144;        // 25600
    float* state   = ws + 287744;        // 262144 (16B aligned)
    float* stats   = ws + 549888;        // 256

    // K1
    k_attnin<<<dim3(BSZ * RNN / 256), dim3(256), 0, stream>>>(hid, ag, ab, a2g, a2b,
                                                              attnin1, attnin2);
    // K2: 25600 waves, 4 waves/block
    k_scores<<<dim3(BSZ * NF / 4), dim3(256), 0, stream>>>(attnin1, attnin2, sfe,
                                                           ascores, out);
    // K3
    k_softmax_small<<<dim3(BSZ), dim3(256), 0, stream>>>(ascores);
    // K4
    k_ctx_state<<<dim3(8, BSZ), dim3(256), 0, stream>>>(hid, ascores, sfe, og, ob, state);
    // K5: big GEMM
    k_gemm<<<dim3((VOCAB + BN - 1) / BN), dim3(256), 0, stream>>>(state, dec_w, dec_b, out);
    // K6
    k_rowstats<<<dim3(BSZ), dim3(256), 0, stream>>>(out, stats);
    // K7
    k_norm<<<dim3((NL + 255) / 256, BSZ), dim3(256), 0, stream>>>(out, stats);
}

// Round 2
// 727.018 us; speedup vs baseline: 1.5509x; 1.5509x over previous
//
#include <hip/hip_runtime.h>
#include <math.h>

#define BSZ 128
#define RNN 1024
#define NF  200
#define VOCAB 50257
#define NL  (VOCAB + NF)   // 50457

typedef __attribute__((ext_vector_type(8))) short bf16x8;
typedef __attribute__((ext_vector_type(4))) float f32x4;

__device__ __forceinline__ ushort f2bf(float f) {
    uint u = __builtin_bit_cast(uint, f);
    uint r = (u + 0x7FFFu + ((u >> 16) & 1u)) >> 16;   // RTNE
    return (ushort)r;
}

// ---------------- K1: attnin1/2 = tanh(h*g + b) ----------------
__global__ void k_attnin(const float* __restrict__ hid,
                         const float* __restrict__ g1, const float* __restrict__ b1,
                         const float* __restrict__ g2, const float* __restrict__ b2,
                         float* __restrict__ a1, float* __restrict__ a2) {
    int i = blockIdx.x * blockDim.x + threadIdx.x;
    int k = i & (RNN - 1);
    float h = hid[i];
    a1[i] = tanhf(h * g1[k] + b1[k]);
    a2[i] = tanhf(h * g2[k] + b2[k]);
}

// ---------------- K2: ascores = a1 @ s^T ; ascores2 -> logits tail ----------------
__global__ void k_scores(const float* __restrict__ a1, const float* __restrict__ a2,
                         const float* __restrict__ s,
                         float* __restrict__ ascores, float* __restrict__ out) {
    int wave = (int)((blockIdx.x * blockDim.x + threadIdx.x) >> 6);
    int lane = threadIdx.x & 63;
    if (wave >= BSZ * NF) return;
    int b = wave / NF, f = wave % NF;
    const float4* sv = (const float4*)(s + (size_t)f * RNN);
    const float4* v1 = (const float4*)(a1 + (size_t)b * RNN);
    const float4* v2 = (const float4*)(a2 + (size_t)b * RNN);
    float acc1 = 0.f, acc2 = 0.f;
    #pragma unroll
    for (int i = lane; i < RNN / 4; i += 64) {
        float4 sx = sv[i], x1 = v1[i], x2 = v2[i];
        acc1 += sx.x * x1.x + sx.y * x1.y + sx.z * x1.z + sx.w * x1.w;
        acc2 += sx.x * x2.x + sx.y * x2.y + sx.z * x2.z + sx.w * x2.w;
    }
    #pragma unroll
    for (int m = 32; m >= 1; m >>= 1) {
        acc1 += __shfl_xor(acc1, m, 64);
        acc2 += __shfl_xor(acc2, m, 64);
    }
    if (lane == 0) {
        ascores[b * NF + f] = acc1;
        out[(size_t)b * NL + VOCAB + f] = acc2;
    }
}

// ---------------- K3: softmax over NF (in place) ----------------
__global__ void k_softmax_small(float* __restrict__ sc) {
    int b = blockIdx.x;
    int t = threadIdx.x;                // 256
    __shared__ float red[256];
    float x = (t < NF) ? sc[b * NF + t] : -INFINITY;
    red[t] = x; __syncthreads();
    for (int s = 128; s >= 1; s >>= 1) {
        if (t < s) red[t] = fmaxf(red[t], red[t + s]);
        __syncthreads();
    }
    float mx = red[0]; __syncthreads();
    float e = (t < NF) ? expf(x - mx) : 0.f;
    red[t] = e; __syncthreads();
    for (int s = 128; s >= 1; s >>= 1) {
        if (t < s) red[t] += red[t + s];
        __syncthreads();
    }
    float inv = 1.f / red[0];
    if (t < NF) sc[b * NF + t] = e * inv;
}

// ---------------- K4: ctx + state = tanh([h,ctx]*og+ob)  -> bf16 ----------------
__global__ void k_ctx_state(const float* __restrict__ hid, const float* __restrict__ aprobs,
                            const float* __restrict__ s, const float* __restrict__ og,
                            const float* __restrict__ ob, ushort* __restrict__ state) {
    int b = blockIdx.y;
    int j = blockIdx.x * 256 + threadIdx.x;   // 0..2047
    __shared__ float ap[NF];
    if (threadIdx.x < NF) ap[threadIdx.x] = aprobs[b * NF + threadIdx.x];
    __syncthreads();
    float v;
    if (j < RNN) {
        v = hid[(size_t)b * RNN + j];
    } else {
        int jj = j - RNN;
        float acc = 0.f;
        #pragma unroll 8
        for (int f = 0; f < NF; ++f) acc += ap[f] * s[(size_t)f * RNN + jj];
        v = acc;
    }
    state[(size_t)b * 2048 + j] = f2bf(tanhf(v * og[j] + ob[j]));
}

// ---------------- K5: logits = state @ W^T + bias (bf16 MFMA) ----------------
// BM=128 (all M), BN=64, BK=64. W: fp32 global -> regs -> bf16 -> swizzled LDS.
// A (state): bf16 in global, fragments read direct (L2-hot).
#define GBN 64
#define GBK 64
__global__ __launch_bounds__(256) void k_gemm_mfma(
        const ushort* __restrict__ Abf,   // 128 x 2048 bf16
        const float*  __restrict__ W,     // VOCAB x 2048 f32
        const float*  __restrict__ bias,
        float* __restrict__ out) {
    __shared__ __align__(16) char Ws[GBN * GBK * 2];   // 8 KB bf16, XOR-swizzled
    int tid = threadIdx.x;
    int lane = tid & 63, wid = tid >> 6;   // 4 waves
    int wm = wid & 1, wn = wid >> 1;       // 2M x 2N split
    int n0 = blockIdx.x * GBN;
    int fr = lane & 15;                    // fragment row/col
    int fk = (lane >> 4) * 8;              // fragment k offset (elems)

    f32x4 acc[4][2] = {};                  // Mrep=4 (wm*64+mr*16), Nrep=2 (wn*32+nr*16)

    for (int k0 = 0; k0 < 2048; k0 += GBK) {
        // stage W tile (64 rows x 64 k) fp32 -> bf16 swizzled LDS
        #pragma unroll
        for (int i = 0; i < 4; ++i) {
            int idx = tid + i * 256;       // 0..1023
            int r = idx >> 4;              // 0..63 (row within tile)
            int k4 = idx & 15;             // float4 index within row
            int n = n0 + r;
            float4 v = make_float4(0.f, 0.f, 0.f, 0.f);
            if (n < VOCAB) v = *(const float4*)(W + (size_t)n * 2048 + k0 + k4 * 4);
            uint2 p;
            p.x = (uint)f2bf(v.x) | ((uint)f2bf(v.y) << 16);
            p.y = (uint)f2bf(v.z) | ((uint)f2bf(v.w) << 16);
            int byte = r * 128 + k4 * 8;
            byte ^= ((r & 7) << 4);        // bank swizzle
            *(uint2*)(Ws + byte) = p;
        }
        __syncthreads();
        #pragma unroll
        for (int kk = 0; kk < 2; ++kk) {   // two K=32 sub-steps
            bf16x8 bfrag[2];
            #pragma unroll
            for (int nr = 0; nr < 2; ++nr) {
                int col = wn * 32 + nr * 16 + fr;
                int byte = col * 128 + (kk * 32 + fk) * 2;
                byte ^= ((col & 7) << 4);
                bfrag[nr] = *(const bf16x8*)(Ws + byte);   // ds_read_b128
            }
            #pragma unroll
            for (int mr = 0; mr < 4; ++mr) {
                int row = wm * 64 + mr * 16 + fr;
                bf16x8 afrag = *(const bf16x8*)(Abf + (size_t)row * 2048 + k0 + kk * 32 + fk);
                #pragma unroll
                for (int nr = 0; nr < 2; ++nr)
                    acc[mr][nr] = __builtin_amdgcn_mfma_f32_16x16x32_bf16(
                        afrag, bfrag[nr], acc[mr][nr], 0, 0, 0);
            }
        }
        __syncthreads();
    }
    // epilogue: D layout col=lane&15, row=(lane>>4)*4+v
    int rbase = (lane >> 4) * 4;
    #pragma unroll
    for (int nr = 0; nr < 2; ++nr) {
        int n = n0 + wn * 32 + nr * 16 + fr;
        if (n < VOCAB) {
            float bv = bias[n];
            #pragma unroll
            for (int mr = 0; mr < 4; ++mr) {
                #pragma unroll
                for (int v = 0; v < 4; ++v) {
                    int m = wm * 64 + mr * 16 + rbase + v;
                    out[(size_t)m * NL + n] = acc[mr][nr][v] + bv;
                }
            }
        }
    }
}

// ---------------- K6: per-row max then sum-exp (2 passes, row L2-hot) ----------------
__global__ void k_rowstats(const float* __restrict__ out, float* __restrict__ stats) {
    int b = blockIdx.x;
    int t = threadIdx.x;   // 512
    const float* row = out + (size_t)b * NL;
    __shared__ float red[512];
    float m = -INFINITY;
    for (int i = t; i < NL; i += 512) m = fmaxf(m, row[i]);
    red[t] = m; __syncthreads();
    for (int s = 256; s >= 1; s >>= 1) {
        if (t < s) red[t] = fmaxf(red[t], red[t + s]);
        __syncthreads();
    }
    m = red[0]; __syncthreads();
    float ssum = 0.f;
    for (int i = t; i < NL; i += 512) ssum += expf(row[i] - m);
    red[t] = ssum; __syncthreads();
    for (int s = 256; s >= 1; s >>= 1) {
        if (t < s) red[t] += red[t + s];
        __syncthreads();
    }
    if (t == 0) { stats[b] = m; stats[BSZ + b] = 1.f / red[0]; }
}

// ---------------- K7: normalize in place ----------------
__global__ void k_norm(float* __restrict__ out, const float* __restrict__ stats) {
    int b = blockIdx.y;
    int i = blockIdx.x * 256 + threadIdx.x;
    if (i < NL) {
        size_t idx = (size_t)b * NL + i;
        out[idx] = expf(out[idx] - stats[b]) * stats[BSZ + b];
    }
}

extern "C" void kernel_launch(void* const* d_in, const int* in_sizes, int n_in,
                              void* d_out, int out_size, void* d_ws, size_t ws_size,
                              hipStream_t stream) {
    const float* hid   = (const float*)d_in[0];
    const float* sfe   = (const float*)d_in[1];
    const float* ag    = (const float*)d_in[2];
    const float* ab    = (const float*)d_in[3];
    const float* og    = (const float*)d_in[4];
    const float* ob    = (const float*)d_in[5];
    const float* a2g   = (const float*)d_in[6];
    const float* a2b   = (const float*)d_in[7];
    const float* dec_w = (const float*)d_in[8];
    const float* dec_b = (const float*)d_in[9];
    float* out = (float*)d_out;

    char* wsb = (char*)d_ws;
    float*  attnin1 = (float*)(wsb);                 // 512 KB
    float*  attnin2 = (float*)(wsb + 524288);        // 512 KB
    float*  ascores = (float*)(wsb + 1048576);       // 100 KB
    ushort* state   = (ushort*)(wsb + 1150976);      // 512 KB bf16
    float*  stats   = (float*)(wsb + 1675264);       // 1 KB

    k_attnin<<<dim3(BSZ * RNN / 256), dim3(256), 0, stream>>>(hid, ag, ab, a2g, a2b,
                                                              attnin1, attnin2);
    k_scores<<<dim3(BSZ * NF / 4), dim3(256), 0, stream>>>(attnin1, attnin2, sfe,
                                                           ascores, out);
    k_softmax_small<<<dim3(BSZ), dim3(256), 0, stream>>>(ascores);
    k_ctx_state<<<dim3(8, BSZ), dim3(256), 0, stream>>>(hid, ascores, sfe, og, ob, state);
    k_gemm_mfma<<<dim3((VOCAB + GBN - 1) / GBN), dim3(256), 0, stream>>>(state, dec_w,
                                                                         dec_b, out);
    k_rowstats<<<dim3(BSZ), dim3(512), 0, stream>>>(out, stats);
    k_norm<<<dim3((NL + 255) / 256, BSZ), dim3(256), 0, stream>>>(out, stats);
}